// Round 1
// baseline (436.936 us; speedup 1.0000x reference)
//
#include <hip/hip_runtime.h>
#include <stdint.h>

// ============================================================================
// ConcreteSelect: Y[b,s] = X[b, argmax_d(logits[s,d] + gumbel(key=42)[s,d])]
// Gumbel-softmax hard=True forward == one-hot column gather of X.
//
// PRNG_VARIANT selects how jax.random's random_bits maps flat index -> u32:
//   1: threefry_partitionable (modern JAX default): x=(hi32(i),lo32(i)), bits=y0^y1
//   0: legacy iota-split-halves: pair (i, i+N/2), bits = y0 (first half) / y1
//   2: partitionable, bits = y0 only
//   3: partitionable, bits = y1 only
// If this round fails with absmax ~O(5), next round: flip to variant 0.
// ============================================================================
#define PRNG_VARIANT 1

#define S_ROWS 256
#define D_COLS 10000
#define B_ROWS 8192
#define HALF_N 1280000u   // (256*10000)/2, for legacy split

__device__ __forceinline__ void threefry2x32(uint32_t& x0, uint32_t& x1) {
  // key = (0, 42) from jax.random.key(42): hi word 0, lo word 42
  const uint32_t k0 = 0u;
  const uint32_t k1 = 42u;
  const uint32_t k2 = 0x1BD11BDAu ^ k0 ^ k1;
  x0 += k0; x1 += k1;
#define TFR(r) { x0 += x1; x1 = (x1 << (r)) | (x1 >> (32 - (r))); x1 ^= x0; }
  TFR(13) TFR(15) TFR(26) TFR(6)   x0 += k1; x1 += k2 + 1u;
  TFR(17) TFR(29) TFR(16) TFR(24)  x0 += k2; x1 += k0 + 2u;
  TFR(13) TFR(15) TFR(26) TFR(6)   x0 += k0; x1 += k1 + 3u;
  TFR(17) TFR(29) TFR(16) TFR(24)  x0 += k1; x1 += k2 + 4u;
  TFR(13) TFR(15) TFR(26) TFR(6)   x0 += k2; x1 += k0 + 5u;
#undef TFR
}

__device__ __forceinline__ uint32_t jax_random_bits(uint32_t i) {
#if PRNG_VARIANT == 0
  uint32_t x0, x1;
  if (i < HALF_N) { x0 = i; x1 = i + HALF_N; }
  else            { x0 = i - HALF_N; x1 = i; }
  threefry2x32(x0, x1);
  return (i < HALF_N) ? x0 : x1;
#else
  uint32_t x0 = 0u;   // hi32 of 64-bit flat index (always 0 here: N < 2^32)
  uint32_t x1 = i;    // lo32
  threefry2x32(x0, x1);
#if PRNG_VARIANT == 2
  return x0;
#elif PRNG_VARIANT == 3
  return x1;
#else
  return x0 ^ x1;
#endif
#endif
}

// jax.random.uniform(minval=tiny, maxval=1) bit-exact, then gumbel = -log(-log(u)).
// Computed in double so rounding can't flip an argmax vs the fp32 reference
// unless the true gap is < ~1e-6.
__device__ __forceinline__ double gumbel_from_bits(uint32_t bits) {
  uint32_t fb = (bits >> 9) | 0x3f800000u;           // float in [1,2)
  float u = __uint_as_float(fb) - 1.0f;              // [0,1), multiples of 2^-23
  if (u <= 0.0f) u = 1.17549435e-38f;                // max(tiny, u) per jax uniform
  double lu = log((double)u);                        // < 0
  return -log(-lu);
}

__global__ __launch_bounds__(256)
void argmax_gumbel_kernel(const float* __restrict__ logits, int* __restrict__ idx_out) {
  const int s   = blockIdx.x;     // 0..255
  const int tid = threadIdx.x;    // 0..255

  double best = -1.0e300;
  int    bi   = 0;
  const int base = s * D_COLS;
  for (int d = tid; d < D_COLS; d += 256) {
    uint32_t bits = jax_random_bits((uint32_t)(base + d));
    double z = (double)logits[base + d] + gumbel_from_bits(bits);
    if (z > best) { best = z; bi = d; }   // d increases within thread -> first-max kept
  }

  __shared__ double sv[256];
  __shared__ int    si[256];
  sv[tid] = best; si[tid] = bi;
  __syncthreads();
  for (int off = 128; off > 0; off >>= 1) {
    if (tid < off) {
      double ov = sv[tid + off]; int oi = si[tid + off];
      // tie-break: lowest index (jnp.argmax first-occurrence semantics)
      if (ov > sv[tid] || (ov == sv[tid] && oi < si[tid])) { sv[tid] = ov; si[tid] = oi; }
    }
    __syncthreads();
  }
  if (tid == 0) idx_out[s] = si[0];
}

#define ROWS_PER_BLOCK 16
__global__ __launch_bounds__(256)
void gather_cols_kernel(const float* __restrict__ X,
                        const int* __restrict__ idx,
                        float* __restrict__ Y) {
  const int s   = threadIdx.x;          // output column 0..255
  const int col = idx[s];               // coalesced 1KB broadcast read
  const long b0 = (long)blockIdx.x * ROWS_PER_BLOCK;
#pragma unroll
  for (int r = 0; r < ROWS_PER_BLOCK; ++r) {
    const long b = b0 + r;
    Y[b * S_ROWS + s] = X[b * D_COLS + col];   // write coalesced, read gathered
  }
}

extern "C" void kernel_launch(void* const* d_in, const int* in_sizes, int n_in,
                              void* d_out, int out_size, void* d_ws, size_t ws_size,
                              hipStream_t stream) {
  const float* X      = (const float*)d_in[0];   // [8192, 10000] fp32
  const float* logits = (const float*)d_in[1];   // [256, 10000] fp32
  float*       Y      = (float*)d_out;           // [8192, 256] fp32
  int*         idx    = (int*)d_ws;              // 256 ints scratch

  argmax_gumbel_kernel<<<S_ROWS, 256, 0, stream>>>(logits, idx);
  gather_cols_kernel<<<B_ROWS / ROWS_PER_BLOCK, 256, 0, stream>>>(X, idx, Y);
}

// Round 2
// 416.545 us; speedup vs baseline: 1.0490x; 1.0490x over previous
//
#include <hip/hip_runtime.h>
#include <stdint.h>

// ============================================================================
// ConcreteSelect: Y[b,s] = X[b, argmax_d(logits[s,d] + gumbel(key=42)[s,d])]
// Gumbel-softmax hard=True forward == one-hot column gather of X.
// PRNG: JAX threefry2x32, partitionable mode: x=(hi32(i),lo32(i)), bits=y0^y1.
// Verified bit-exact in round 1 (absmax 0.0).
//
// Argmax strategy: float fast path (logf) over all 10000 cols with z values
// staged in LDS; any column within EPS=1e-3 of the float max (float error is
// <= ~1e-5) is re-evaluated in double, which makes the final decision. This
// keeps round-1's double-precision argmax semantics at ~1/50th the cost.
// ============================================================================

#define S_ROWS 256
#define D_COLS 10000
#define B_ROWS 8192

__device__ __forceinline__ void threefry2x32(uint32_t& x0, uint32_t& x1) {
  const uint32_t k0 = 0u;
  const uint32_t k1 = 42u;
  const uint32_t k2 = 0x1BD11BDAu ^ k0 ^ k1;
  x0 += k0; x1 += k1;
#define TFR(r) { x0 += x1; x1 = (x1 << (r)) | (x1 >> (32 - (r))); x1 ^= x0; }
  TFR(13) TFR(15) TFR(26) TFR(6)   x0 += k1; x1 += k2 + 1u;
  TFR(17) TFR(29) TFR(16) TFR(24)  x0 += k2; x1 += k0 + 2u;
  TFR(13) TFR(15) TFR(26) TFR(6)   x0 += k0; x1 += k1 + 3u;
  TFR(17) TFR(29) TFR(16) TFR(24)  x0 += k1; x1 += k2 + 4u;
  TFR(13) TFR(15) TFR(26) TFR(6)   x0 += k2; x1 += k0 + 5u;
#undef TFR
}

__device__ __forceinline__ uint32_t jax_random_bits(uint32_t i) {
  uint32_t x0 = 0u, x1 = i;
  threefry2x32(x0, x1);
  return x0 ^ x1;
}

__device__ __forceinline__ float uniform_from_bits(uint32_t bits) {
  uint32_t fb = (bits >> 9) | 0x3f800000u;     // [1,2)
  float u = __uint_as_float(fb) - 1.0f;        // [0,1)
  if (u <= 0.0f) u = 1.17549435e-38f;          // max(tiny, u)
  return u;
}

__device__ __forceinline__ float gumbel_f(uint32_t bits) {
  float u  = uniform_from_bits(bits);
  float nl = -logf(u);                          // > 0
  return -logf(nl);
}

__device__ __forceinline__ double gumbel_d(uint32_t bits) {
  float u = uniform_from_bits(bits);
  double lu = log((double)u);
  return -log(-lu);
}

#define ARGMAX_THREADS 1024
#define CAND_MAX 64

__global__ __launch_bounds__(ARGMAX_THREADS)
void argmax_gumbel_kernel(const float* __restrict__ logits, int* __restrict__ idx_out) {
  const int s   = blockIdx.x;      // 0..255
  const int tid = threadIdx.x;     // 0..1023
  const int base = s * D_COLS;

  __shared__ float zbuf[D_COLS];                 // 40 KB
  __shared__ float sv[ARGMAX_THREADS];           // 4 KB
  __shared__ int   si[ARGMAX_THREADS];           // 4 KB
  __shared__ int   n_cand;
  __shared__ int   cand[CAND_MAX];

  if (tid == 0) n_cand = 0;

  float best = -1.0e30f;
  int   bi   = 0;
  for (int d = tid; d < D_COLS; d += ARGMAX_THREADS) {
    uint32_t bits = jax_random_bits((uint32_t)(base + d));
    float z = logits[base + d] + gumbel_f(bits);
    zbuf[d] = z;
    if (z > best) { best = z; bi = d; }
  }
  sv[tid] = best; si[tid] = bi;
  __syncthreads();
  for (int off = ARGMAX_THREADS / 2; off > 0; off >>= 1) {
    if (tid < off) {
      float ov = sv[tid + off]; int oi = si[tid + off];
      if (ov > sv[tid] || (ov == sv[tid] && oi < si[tid])) { sv[tid] = ov; si[tid] = oi; }
    }
    __syncthreads();
  }

  // Collect all columns within EPS of the float max; double precision decides.
  const float thresh = sv[0] - 1.0e-3f;
  for (int d = tid; d < D_COLS; d += ARGMAX_THREADS) {
    if (zbuf[d] >= thresh) {
      int pos = atomicAdd(&n_cand, 1);
      if (pos < CAND_MAX) cand[pos] = d;
    }
  }
  __syncthreads();

  if (tid == 0) {
    int    nc   = n_cand < CAND_MAX ? n_cand : CAND_MAX;
    double bz   = -1.0e300;
    int    bidx = 0x7fffffff;
    for (int i = 0; i < nc; ++i) {
      int d = cand[i];
      double z = (double)logits[base + d] + gumbel_d(jax_random_bits((uint32_t)(base + d)));
      if (z > bz || (z == bz && d < bidx)) { bz = z; bidx = d; }  // first-occurrence tie-break
    }
    idx_out[s] = bidx;
  }
}

#define ROWS_PER_BLOCK 8
__global__ __launch_bounds__(256)
void gather_cols_kernel(const float* __restrict__ X,
                        const int* __restrict__ idx,
                        float* __restrict__ Y) {
  const int s   = threadIdx.x;           // output column 0..255
  const int col = idx[s];                // 1 KB broadcast, L2-resident
  const long b0 = (long)blockIdx.x * ROWS_PER_BLOCK;
  float v[ROWS_PER_BLOCK];
#pragma unroll
  for (int r = 0; r < ROWS_PER_BLOCK; ++r)
    v[r] = X[(b0 + r) * D_COLS + col];   // all loads issued before stores (MLP)
#pragma unroll
  for (int r = 0; r < ROWS_PER_BLOCK; ++r)
    Y[(b0 + r) * S_ROWS + s] = v[r];     // coalesced 1 KB per row
}

extern "C" void kernel_launch(void* const* d_in, const int* in_sizes, int n_in,
                              void* d_out, int out_size, void* d_ws, size_t ws_size,
                              hipStream_t stream) {
  const float* X      = (const float*)d_in[0];   // [8192, 10000] fp32
  const float* logits = (const float*)d_in[1];   // [256, 10000] fp32
  float*       Y      = (float*)d_out;           // [8192, 256] fp32
  int*         idx    = (int*)d_ws;              // 256 ints scratch

  argmax_gumbel_kernel<<<S_ROWS, ARGMAX_THREADS, 0, stream>>>(logits, idx);
  gather_cols_kernel<<<B_ROWS / ROWS_PER_BLOCK, 256, 0, stream>>>(X, idx, Y);
}